// Round 8
// baseline (278.682 us; speedup 1.0000x reference)
//
#include <hip/hip_runtime.h>

#define NNODES 100000
#define NBUCK 391                 // ceil(100000/256) buckets of 256 nodes (dst>>8)
#define NB_CHUNK 256              // edge chunks for counting sort
#define NC (NBUCK * NB_CHUNK)     // count-matrix size = 100096
#define SCAN_ELEMS 1024           // elements per scan block (256 threads x 4)

// ---------------- edge dtype sniffer (int64 vs int32) ----------------
__global__ void detect_kernel(const int* __restrict__ raw, int* __restrict__ flag) {
    __shared__ int cnt;
    if (threadIdx.x == 0) cnt = 0;
    __syncthreads();
    if (threadIdx.x < 100) {
        if (raw[2 * threadIdx.x + 1] == 0) atomicAdd(&cnt, 1);
    }
    __syncthreads();
    if (threadIdx.x == 0) *flag = (cnt > 50) ? 1 : 0;
}

// ---------------- counting sort pass 1: per-chunk bucket histogram ----------------
__global__ __launch_bounds__(256) void count_kernel(const int* __restrict__ raw,
                                                    int* __restrict__ counts,
                                                    int E, int CE, const int* __restrict__ flag) {
    __shared__ int hist[NBUCK];
    for (int i = threadIdx.x; i < NBUCK; i += 256) hist[i] = 0;
    __syncthreads();
    int b = blockIdx.x;
    int isI64 = *flag;
    int beg = b * CE;
    int end = beg + CE; if (end > E) end = E;
    for (int e = beg + (int)threadIdx.x; e < end; e += 256) {
        int d = isI64 ? raw[2 * E + 2 * e] : raw[E + e];
        atomicAdd(&hist[d >> 8], 1);              // LDS atomic
    }
    __syncthreads();
    for (int k = threadIdx.x; k < NBUCK; k += 256)
        counts[k * NB_CHUNK + b] = hist[k];       // bucket-major for linear scan
}

// ---------------- device-wide exclusive scan (generic) ----------------
__global__ __launch_bounds__(256) void scan_partial_kernel(const int* __restrict__ in,
                                                           int* __restrict__ bsum, int n) {
    int base = blockIdx.x * SCAN_ELEMS + threadIdx.x * 4;
    int s = 0;
    if (base + 3 < n) {
        int4 v = *reinterpret_cast<const int4*>(&in[base]);
        s = v.x + v.y + v.z + v.w;
    } else {
        for (int i = base; i < n && i < base + 4; ++i) s += in[i];
    }
#pragma unroll
    for (int d = 32; d; d >>= 1) s += __shfl_down(s, d, 64);
    __shared__ int ws[4];
    int wid = threadIdx.x >> 6;
    if ((threadIdx.x & 63) == 0) ws[wid] = s;
    __syncthreads();
    if (threadIdx.x == 0) bsum[blockIdx.x] = ws[0] + ws[1] + ws[2] + ws[3];
}

__global__ void scan_partials_kernel(const int* __restrict__ bsum, int* __restrict__ boff,
                                     int* __restrict__ total_out, int nb) {
    __shared__ int s[128];
    int t = threadIdx.x;
    s[t] = (t < nb) ? bsum[t] : 0;
    __syncthreads();
    for (int d = 1; d < 128; d <<= 1) {
        int v = (t >= d) ? s[t - d] : 0;
        __syncthreads();
        s[t] += v;
        __syncthreads();
    }
    if (t < nb) boff[t] = (t == 0) ? 0 : s[t - 1];
    if (t == 127) *total_out = s[127];
}

__global__ __launch_bounds__(256) void scan_write_kernel(const int* __restrict__ in,
                                                         const int* __restrict__ boff,
                                                         int* __restrict__ outp, int n) {
    __shared__ int ts[256];
    int base = blockIdx.x * SCAN_ELEMS + threadIdx.x * 4;
    int v0 = 0, v1 = 0, v2 = 0, v3 = 0;
    if (base + 3 < n) {
        int4 v = *reinterpret_cast<const int4*>(&in[base]);
        v0 = v.x; v1 = v.y; v2 = v.z; v3 = v.w;
    } else {
        if (base < n)     v0 = in[base];
        if (base + 1 < n) v1 = in[base + 1];
        if (base + 2 < n) v2 = in[base + 2];
    }
    ts[threadIdx.x] = v0 + v1 + v2 + v3;
    __syncthreads();
    for (int d = 1; d < 256; d <<= 1) {
        int t = (threadIdx.x >= d) ? ts[threadIdx.x - d] : 0;
        __syncthreads();
        ts[threadIdx.x] += t;
        __syncthreads();
    }
    int run = boff[blockIdx.x] + ((threadIdx.x == 0) ? 0 : ts[threadIdx.x - 1]);
    if (base < n)     { outp[base] = run;     run += v0; }
    if (base + 1 < n) { outp[base + 1] = run; run += v1; }
    if (base + 2 < n) { outp[base + 2] = run; run += v2; }
    if (base + 3 < n) { outp[base + 3] = run; }
}

// ---------------- counting sort pass 2: scatter (packed: src | (d&255)<<24) ----------------
// src fits 17 bits (NNODES < 2^17); bits 17-23 zero; local dst id in bits 24-31.
__global__ __launch_bounds__(256) void scatter_kernel(const int* __restrict__ raw,
                                                      const int* __restrict__ cbase,
                                                      int* __restrict__ cw,
                                                      int E, int CE, const int* __restrict__ flag) {
    __shared__ int cur[NBUCK];
    int b = blockIdx.x;
    for (int k = threadIdx.x; k < NBUCK; k += 256)
        cur[k] = cbase[k * NB_CHUNK + b];
    __syncthreads();
    int isI64 = *flag;
    int beg = b * CE;
    int end = beg + CE; if (end > E) end = E;
    for (int e = beg + (int)threadIdx.x; e < end; e += 256) {
        int s, d;
        if (isI64) { s = raw[2 * e]; d = raw[2 * E + 2 * e]; }
        else       { s = raw[e];     d = raw[E + e]; }
        int pos = atomicAdd(&cur[d >> 8], 1);     // LDS atomic
        cw[pos] = s | ((d & 255) << 24);          // single-CU contiguous run per bucket
    }
}

// ---------------- per-bucket degree histogram + dinv (coalesced, atomic-free) ----------------
__global__ __launch_bounds__(256) void histdeg_kernel(const int* __restrict__ cw,
                                                      const int* __restrict__ cbase,
                                                      int* __restrict__ indeg,
                                                      float* __restrict__ dinv, int n) {
    __shared__ int hist[256];
    hist[threadIdx.x] = 0;
    __syncthreads();
    int k = blockIdx.x;
    int beg = cbase[k * NB_CHUNK];
    int end = cbase[(k + 1) * NB_CHUNK];
    for (int e = beg + (int)threadIdx.x; e < end; e += 256)
        atomicAdd(&hist[(cw[e] >> 24) & 255], 1); // LDS atomic
    __syncthreads();
    int i = (k << 8) + threadIdx.x;
    if (i < n) {
        int dg = hist[threadIdx.x];
        indeg[i] = dg;
        dinv[i] = rsqrtf((float)(dg + 1));        // +1 self loop; always > 0
    }
}

// ---------------- per-bucket CSR col fill (LDS cursors, single-CU-owned window) ----------------
__global__ __launch_bounds__(256) void fillcol_kernel(const int* __restrict__ cw,
                                                      const int* __restrict__ cbase,
                                                      const int* __restrict__ ptr,
                                                      int* __restrict__ col, int n) {
    __shared__ int cur[256];
    int k = blockIdx.x;
    int i = (k << 8) + threadIdx.x;
    cur[threadIdx.x] = (i < n) ? ptr[i] : 0;
    __syncthreads();
    int beg = cbase[k * NB_CHUNK];
    int end = cbase[(k + 1) * NB_CHUNK];
    for (int e = beg + (int)threadIdx.x; e < end; e += 256) {
        int v = cw[e];
        int pos = atomicAdd(&cur[(v >> 24) & 255], 1); // LDS atomic; pos is global index
        col[pos] = v & 0x00FFFFFF;
    }
}

// ---------------- GEMM1: [M,256] @ [256,64] -> [M,64] ----------------
// W-only in LDS; x streamed global->register (each x row feeds exactly one output
// row; L1 reuses each 64B line across 4 consecutive k-steps). 8x8 register tile,
// 128 threads = 16 ty x 8 tx, BM=128 -> FMA-bound (LDS: 2 b128/kk per thread).
__global__ __launch_bounds__(128) void gemm1_kernel(const float* __restrict__ x,
                                                    const float* __restrict__ W,
                                                    float* __restrict__ H, int M) {
    __shared__ float ws[64][68];
    int tid = threadIdx.x;
    int tx = tid & 7;              // 8 col-groups of 8 -> 64 cols
    int ty = tid >> 3;             // 16 row-groups of 8 -> 128 rows
    int bm = blockIdx.x * 128;
    const float4* x4 = reinterpret_cast<const float4*>(x);
    int rowbase[8];
    bool rowok[8];
#pragma unroll
    for (int i = 0; i < 8; ++i) {
        int r = bm + ty * 8 + i;
        rowok[i] = r < M;
        rowbase[i] = (rowok[i] ? r : (M - 1)) * 64;   // 64 float4 per row
    }
    float acc[8][8] = {};
    float4 xa[8], xb[8];
    for (int kt = 0; kt < 4; ++kt) {                  // K-tiles of 64
#pragma unroll
        for (int i = 0; i < 8; ++i) {                 // stage W tile: 1024 float4 / 128 thr
            int lin = (tid << 3) + i;
            int r = lin >> 4;
            int c = (lin & 15) << 2;
            *reinterpret_cast<float4*>(&ws[r][c]) =
                *reinterpret_cast<const float4*>(&W[(size_t)(kt * 64 + r) * 64 + c]);
        }
        __syncthreads();
        int k4base = kt * 16;
#pragma unroll
        for (int i = 0; i < 8; ++i) xa[i] = x4[rowbase[i] + k4base];
        for (int k4 = 0; k4 < 16; ++k4) {
            if (k4 < 15) {
#pragma unroll
                for (int i = 0; i < 8; ++i) xb[i] = x4[rowbase[i] + k4base + k4 + 1];
            }
#pragma unroll
            for (int kk = 0; kk < 4; ++kk) {
                float4 b0 = *reinterpret_cast<const float4*>(&ws[k4 * 4 + kk][tx * 8]);
                float4 b1 = *reinterpret_cast<const float4*>(&ws[k4 * 4 + kk][tx * 8 + 4]);
                float bb0 = b0.x, bb1 = b0.y, bb2 = b0.z, bb3 = b0.w;
                float bb4 = b1.x, bb5 = b1.y, bb6 = b1.z, bb7 = b1.w;
#pragma unroll
                for (int i = 0; i < 8; ++i) {
                    float a = (kk == 0) ? xa[i].x : (kk == 1) ? xa[i].y
                            : (kk == 2) ? xa[i].z : xa[i].w;
                    acc[i][0] = fmaf(a, bb0, acc[i][0]);
                    acc[i][1] = fmaf(a, bb1, acc[i][1]);
                    acc[i][2] = fmaf(a, bb2, acc[i][2]);
                    acc[i][3] = fmaf(a, bb3, acc[i][3]);
                    acc[i][4] = fmaf(a, bb4, acc[i][4]);
                    acc[i][5] = fmaf(a, bb5, acc[i][5]);
                    acc[i][6] = fmaf(a, bb6, acc[i][6]);
                    acc[i][7] = fmaf(a, bb7, acc[i][7]);
                }
            }
#pragma unroll
            for (int i = 0; i < 8; ++i) xa[i] = xb[i];
        }
        __syncthreads();
    }
#pragma unroll
    for (int i = 0; i < 8; ++i) {
        if (!rowok[i]) continue;
        int r = bm + ty * 8 + i;
        float4 o0 = make_float4(acc[i][0], acc[i][1], acc[i][2], acc[i][3]);
        float4 o1 = make_float4(acc[i][4], acc[i][5], acc[i][6], acc[i][7]);
        *reinterpret_cast<float4*>(&H[(size_t)r * 64 + tx * 8]) = o0;
        *reinterpret_cast<float4*>(&H[(size_t)r * 64 + tx * 8 + 4]) = o1;
    }
}

// ---------------- aggregation, quarter-wave version (col-only CSR) ----------------
__global__ __launch_bounds__(256) void aggregate_kernel(const float* __restrict__ h,
                                                        const int* __restrict__ ptr,
                                                        const int* __restrict__ col,
                                                        const float* __restrict__ dinv,
                                                        const float* __restrict__ bias,
                                                        float* __restrict__ out, int n, int relu) {
    int node = (blockIdx.x << 2) + (threadIdx.x >> 6);
    if (node >= n) return;
    int lane = threadIdx.x & 63;
    int q    = lane >> 4;              // quarter-wave id 0..3
    int fl   = (lane & 15) << 2;       // feature base 0,4,...,60
    float4 acc = make_float4(0.f, 0.f, 0.f, 0.f);
    int pend = ptr[node + 1];
    int p = ptr[node] + q;             // quarter q takes edges q, q+4, q+8, ...
    for (; p + 4 < pend; p += 8) {     // unroll 2: p and p+4 both valid
        int c0 = col[p];
        int c1 = col[p + 4];
        float4 h0 = *reinterpret_cast<const float4*>(&h[(size_t)c0 * 64 + fl]);
        float4 h1 = *reinterpret_cast<const float4*>(&h[(size_t)c1 * 64 + fl]);
        float w0 = dinv[c0], w1 = dinv[c1];
        acc.x = fmaf(w0, h0.x, acc.x); acc.y = fmaf(w0, h0.y, acc.y);
        acc.z = fmaf(w0, h0.z, acc.z); acc.w = fmaf(w0, h0.w, acc.w);
        acc.x = fmaf(w1, h1.x, acc.x); acc.y = fmaf(w1, h1.y, acc.y);
        acc.z = fmaf(w1, h1.z, acc.z); acc.w = fmaf(w1, h1.w, acc.w);
    }
    if (p < pend) {
        int c0 = col[p];
        float4 h0 = *reinterpret_cast<const float4*>(&h[(size_t)c0 * 64 + fl]);
        float w0 = dinv[c0];
        acc.x = fmaf(w0, h0.x, acc.x); acc.y = fmaf(w0, h0.y, acc.y);
        acc.z = fmaf(w0, h0.z, acc.z); acc.w = fmaf(w0, h0.w, acc.w);
    }
    acc.x += __shfl_xor(acc.x, 16, 64); acc.y += __shfl_xor(acc.y, 16, 64);
    acc.z += __shfl_xor(acc.z, 16, 64); acc.w += __shfl_xor(acc.w, 16, 64);
    acc.x += __shfl_xor(acc.x, 32, 64); acc.y += __shfl_xor(acc.y, 32, 64);
    acc.z += __shfl_xor(acc.z, 32, 64); acc.w += __shfl_xor(acc.w, 32, 64);
    if (q == 0) {
        float di = dinv[node];
        float4 sv = *reinterpret_cast<const float4*>(&h[(size_t)node * 64 + fl]);
        acc.x = fmaf(di, sv.x, acc.x); acc.y = fmaf(di, sv.y, acc.y);
        acc.z = fmaf(di, sv.z, acc.z); acc.w = fmaf(di, sv.w, acc.w);
        float4 v;
        v.x = acc.x * di; v.y = acc.y * di; v.z = acc.z * di; v.w = acc.w * di;
        if (bias) {
            float4 bv = *reinterpret_cast<const float4*>(&bias[fl]);
            v.x += bv.x; v.y += bv.y; v.z += bv.z; v.w += bv.w;
        }
        if (relu) {
            v.x = fmaxf(v.x, 0.f); v.y = fmaxf(v.y, 0.f);
            v.z = fmaxf(v.z, 0.f); v.w = fmaxf(v.w, 0.f);
        }
        *reinterpret_cast<float4*>(&out[(size_t)node * 64 + fl]) = v;
    }
}

// ---------------- GEMM2: [M,64] @ [64,128] + b -> [M,128] ----------------
__global__ __launch_bounds__(256) void gemm2_kernel(const float* __restrict__ A,
                                                    const float* __restrict__ W,
                                                    const float* __restrict__ bias,
                                                    float* __restrict__ out, int M) {
    __shared__ float as[64][65];
    __shared__ float ws[64][128];
    int tid = threadIdx.x;
    int bm = blockIdx.x * 64;
    int ty = tid >> 4, tx = tid & 15;
#pragma unroll
    for (int i = 0; i < 4; ++i) {
        int lin = (tid << 2) + i;
        int r = lin >> 4;
        int c = (lin & 15) << 2;
        float4 v = make_float4(0.f, 0.f, 0.f, 0.f);
        int gr = bm + r;
        if (gr < M) v = *reinterpret_cast<const float4*>(&A[(size_t)gr * 64 + c]);
        as[r][c] = v.x; as[r][c + 1] = v.y; as[r][c + 2] = v.z; as[r][c + 3] = v.w;
    }
#pragma unroll
    for (int i = 0; i < 8; ++i) {
        int lin = tid + (i << 8);
        int r = lin >> 5;
        int c = (lin & 31) << 2;
        *reinterpret_cast<float4*>(&ws[r][c]) =
            *reinterpret_cast<const float4*>(&W[(size_t)r * 128 + c]);
    }
    __syncthreads();
    float acc[4][8] = {};
#pragma unroll 8
    for (int kk = 0; kk < 64; ++kk) {
        float a[4];
#pragma unroll
        for (int i = 0; i < 4; ++i) a[i] = as[ty * 4 + i][kk];
        float b[8];
        float4 b0 = *reinterpret_cast<const float4*>(&ws[kk][tx * 8]);
        float4 b1 = *reinterpret_cast<const float4*>(&ws[kk][tx * 8 + 4]);
        b[0] = b0.x; b[1] = b0.y; b[2] = b0.z; b[3] = b0.w;
        b[4] = b1.x; b[5] = b1.y; b[6] = b1.z; b[7] = b1.w;
#pragma unroll
        for (int i = 0; i < 4; ++i)
#pragma unroll
            for (int j = 0; j < 8; ++j)
                acc[i][j] = fmaf(a[i], b[j], acc[i][j]);
    }
#pragma unroll
    for (int i = 0; i < 4; ++i) {
        int gr = bm + ty * 4 + i;
        if (gr >= M) continue;
#pragma unroll
        for (int jv = 0; jv < 2; ++jv) {
            int cbase = tx * 8 + jv * 4;
            float4 o;
            o.x = acc[i][jv * 4 + 0] + bias[cbase + 0];
            o.y = acc[i][jv * 4 + 1] + bias[cbase + 1];
            o.z = acc[i][jv * 4 + 2] + bias[cbase + 2];
            o.w = acc[i][jv * 4 + 3] + bias[cbase + 3];
            *reinterpret_cast<float4*>(&out[(size_t)gr * 128 + cbase]) = o;
        }
    }
}

extern "C" void kernel_launch(void* const* d_in, const int* in_sizes, int n_in,
                              void* d_out, int out_size, void* d_ws, size_t ws_size,
                              hipStream_t stream) {
    const float* x  = (const float*)d_in[0];
    const int*   ei = (const int*)d_in[1];
    const float* W1 = (const float*)d_in[2];
    const float* b1 = (const float*)d_in[3];
    const float* W2 = (const float*)d_in[4];
    const float* b2 = (const float*)d_in[5];
    float* out = (float*)d_out;
    const int n = NNODES;
    const int E = in_sizes[1] / 2;
    const int CE = (E + NB_CHUNK - 1) / NB_CHUNK;

    char* w = (char*)d_ws;
    auto alloc = [&](size_t bytes) {
        char* p = w;
        w += (bytes + 255) & ~(size_t)255;
        return p;
    };
    int*   flag   = (int*)  alloc(4);
    int*   counts = (int*)  alloc((size_t)NC * 4);
    int*   cbase  = (int*)  alloc((size_t)(NC + 1) * 4);
    int*   indeg  = (int*)  alloc((size_t)n * 4);
    float* dinv   = (float*)alloc((size_t)n * 4);
    int*   ptr    = (int*)  alloc((size_t)(n + 1) * 4);
    int*   bsum   = (int*)  alloc(128 * 4);
    int*   boff   = (int*)  alloc(128 * 4);
    int*   cw     = (int*)  alloc((size_t)E * 4);
    int*   col    = (int*)  alloc((size_t)E * 4);
    float* H1     = (float*)alloc((size_t)n * 64 * 4);
    float* h1     = (float*)alloc((size_t)n * 64 * 4);
    float* A2     = H1;   // H1 dead after first aggregation

    int sbC = (NC + SCAN_ELEMS - 1) / SCAN_ELEMS;   // 98
    int sbN = (n  + SCAN_ELEMS - 1) / SCAN_ELEMS;   // 98

    detect_kernel<<<1, 128, 0, stream>>>(ei, flag);
    count_kernel<<<NB_CHUNK, 256, 0, stream>>>(ei, counts, E, CE, flag);
    scan_partial_kernel<<<sbC, 256, 0, stream>>>(counts, bsum, NC);
    scan_partials_kernel<<<1, 128, 0, stream>>>(bsum, boff, &cbase[NC], sbC);
    scan_write_kernel<<<sbC, 256, 0, stream>>>(counts, boff, cbase, NC);
    scatter_kernel<<<NB_CHUNK, 256, 0, stream>>>(ei, cbase, cw, E, CE, flag);
    histdeg_kernel<<<NBUCK, 256, 0, stream>>>(cw, cbase, indeg, dinv, n);
    scan_partial_kernel<<<sbN, 256, 0, stream>>>(indeg, bsum, n);
    scan_partials_kernel<<<1, 128, 0, stream>>>(bsum, boff, &ptr[n], sbN);
    scan_write_kernel<<<sbN, 256, 0, stream>>>(indeg, boff, ptr, n);
    fillcol_kernel<<<NBUCK, 256, 0, stream>>>(cw, cbase, ptr, col, n);

    gemm1_kernel<<<(n + 127) / 128, 128, 0, stream>>>(x, W1, H1, n);
    aggregate_kernel<<<(n + 3) / 4, 256, 0, stream>>>(H1, ptr, col, dinv, b1, h1, n, 1);
    aggregate_kernel<<<(n + 3) / 4, 256, 0, stream>>>(h1, ptr, col, dinv, nullptr, A2, n, 0);
    gemm2_kernel<<<(n + 63) / 64, 256, 0, stream>>>(A2, W2, b2, out, n);
}

// Round 9
// 238.939 us; speedup vs baseline: 1.1663x; 1.1663x over previous
//
#include <hip/hip_runtime.h>
#include <hip/hip_fp16.h>

#define NNODES 100000
#define NBUCK 391                 // ceil(100000/256) buckets of 256 nodes (dst>>8)
#define NB_CHUNK 256              // edge chunks for counting sort
#define NC (NBUCK * NB_CHUNK)     // count-matrix size = 100096
#define SCAN_ELEMS 1024           // elements per scan block (256 threads x 4)

// ---------------- edge dtype sniffer (int64 vs int32) ----------------
__global__ void detect_kernel(const int* __restrict__ raw, int* __restrict__ flag) {
    __shared__ int cnt;
    if (threadIdx.x == 0) cnt = 0;
    __syncthreads();
    if (threadIdx.x < 100) {
        if (raw[2 * threadIdx.x + 1] == 0) atomicAdd(&cnt, 1);
    }
    __syncthreads();
    if (threadIdx.x == 0) *flag = (cnt > 50) ? 1 : 0;
}

// ---------------- counting sort pass 1: per-chunk bucket histogram ----------------
__global__ __launch_bounds__(256) void count_kernel(const int* __restrict__ raw,
                                                    int* __restrict__ counts,
                                                    int E, int CE, const int* __restrict__ flag) {
    __shared__ int hist[NBUCK];
    for (int i = threadIdx.x; i < NBUCK; i += 256) hist[i] = 0;
    __syncthreads();
    int b = blockIdx.x;
    int isI64 = *flag;
    int beg = b * CE;
    int end = beg + CE; if (end > E) end = E;
    for (int e = beg + (int)threadIdx.x; e < end; e += 256) {
        int d = isI64 ? raw[2 * E + 2 * e] : raw[E + e];
        atomicAdd(&hist[d >> 8], 1);              // LDS atomic
    }
    __syncthreads();
    for (int k = threadIdx.x; k < NBUCK; k += 256)
        counts[k * NB_CHUNK + b] = hist[k];       // bucket-major for linear scan
}

// ---------------- device-wide exclusive scan (generic) ----------------
__global__ __launch_bounds__(256) void scan_partial_kernel(const int* __restrict__ in,
                                                           int* __restrict__ bsum, int n) {
    int base = blockIdx.x * SCAN_ELEMS + threadIdx.x * 4;
    int s = 0;
    if (base + 3 < n) {
        int4 v = *reinterpret_cast<const int4*>(&in[base]);
        s = v.x + v.y + v.z + v.w;
    } else {
        for (int i = base; i < n && i < base + 4; ++i) s += in[i];
    }
#pragma unroll
    for (int d = 32; d; d >>= 1) s += __shfl_down(s, d, 64);
    __shared__ int ws[4];
    int wid = threadIdx.x >> 6;
    if ((threadIdx.x & 63) == 0) ws[wid] = s;
    __syncthreads();
    if (threadIdx.x == 0) bsum[blockIdx.x] = ws[0] + ws[1] + ws[2] + ws[3];
}

__global__ void scan_partials_kernel(const int* __restrict__ bsum, int* __restrict__ boff,
                                     int* __restrict__ total_out, int nb) {
    __shared__ int s[128];
    int t = threadIdx.x;
    s[t] = (t < nb) ? bsum[t] : 0;
    __syncthreads();
    for (int d = 1; d < 128; d <<= 1) {
        int v = (t >= d) ? s[t - d] : 0;
        __syncthreads();
        s[t] += v;
        __syncthreads();
    }
    if (t < nb) boff[t] = (t == 0) ? 0 : s[t - 1];
    if (t == 127) *total_out = s[127];
}

__global__ __launch_bounds__(256) void scan_write_kernel(const int* __restrict__ in,
                                                         const int* __restrict__ boff,
                                                         int* __restrict__ outp, int n) {
    __shared__ int ts[256];
    int base = blockIdx.x * SCAN_ELEMS + threadIdx.x * 4;
    int v0 = 0, v1 = 0, v2 = 0, v3 = 0;
    if (base + 3 < n) {
        int4 v = *reinterpret_cast<const int4*>(&in[base]);
        v0 = v.x; v1 = v.y; v2 = v.z; v3 = v.w;
    } else {
        if (base < n)     v0 = in[base];
        if (base + 1 < n) v1 = in[base + 1];
        if (base + 2 < n) v2 = in[base + 2];
    }
    ts[threadIdx.x] = v0 + v1 + v2 + v3;
    __syncthreads();
    for (int d = 1; d < 256; d <<= 1) {
        int t = (threadIdx.x >= d) ? ts[threadIdx.x - d] : 0;
        __syncthreads();
        ts[threadIdx.x] += t;
        __syncthreads();
    }
    int run = boff[blockIdx.x] + ((threadIdx.x == 0) ? 0 : ts[threadIdx.x - 1]);
    if (base < n)     { outp[base] = run;     run += v0; }
    if (base + 1 < n) { outp[base + 1] = run; run += v1; }
    if (base + 2 < n) { outp[base + 2] = run; run += v2; }
    if (base + 3 < n) { outp[base + 3] = run; }
}

// ---------------- counting sort pass 2: scatter (packed: src | (d&255)<<24) ----------------
__global__ __launch_bounds__(256) void scatter_kernel(const int* __restrict__ raw,
                                                      const int* __restrict__ cbase,
                                                      int* __restrict__ cw,
                                                      int E, int CE, const int* __restrict__ flag) {
    __shared__ int cur[NBUCK];
    int b = blockIdx.x;
    for (int k = threadIdx.x; k < NBUCK; k += 256)
        cur[k] = cbase[k * NB_CHUNK + b];
    __syncthreads();
    int isI64 = *flag;
    int beg = b * CE;
    int end = beg + CE; if (end > E) end = E;
    for (int e = beg + (int)threadIdx.x; e < end; e += 256) {
        int s, d;
        if (isI64) { s = raw[2 * e]; d = raw[2 * E + 2 * e]; }
        else       { s = raw[e];     d = raw[E + e]; }
        int pos = atomicAdd(&cur[d >> 8], 1);     // LDS atomic
        cw[pos] = s | ((d & 255) << 24);          // single-CU contiguous run per bucket
    }
}

// ---------------- per-bucket degree histogram + dinv (coalesced, atomic-free) ----------------
__global__ __launch_bounds__(256) void histdeg_kernel(const int* __restrict__ cw,
                                                      const int* __restrict__ cbase,
                                                      int* __restrict__ indeg,
                                                      float* __restrict__ dinv, int n) {
    __shared__ int hist[256];
    hist[threadIdx.x] = 0;
    __syncthreads();
    int k = blockIdx.x;
    int beg = cbase[k * NB_CHUNK];
    int end = cbase[(k + 1) * NB_CHUNK];
    for (int e = beg + (int)threadIdx.x; e < end; e += 256)
        atomicAdd(&hist[(cw[e] >> 24) & 255], 1); // LDS atomic
    __syncthreads();
    int i = (k << 8) + threadIdx.x;
    if (i < n) {
        int dg = hist[threadIdx.x];
        indeg[i] = dg;
        dinv[i] = rsqrtf((float)(dg + 1));        // +1 self loop; always > 0
    }
}

// ---------------- per-bucket CSR col fill (LDS cursors, single-CU-owned window) ----------------
__global__ __launch_bounds__(256) void fillcol_kernel(const int* __restrict__ cw,
                                                      const int* __restrict__ cbase,
                                                      const int* __restrict__ ptr,
                                                      int* __restrict__ col, int n) {
    __shared__ int cur[256];
    int k = blockIdx.x;
    int i = (k << 8) + threadIdx.x;
    cur[threadIdx.x] = (i < n) ? ptr[i] : 0;
    __syncthreads();
    int beg = cbase[k * NB_CHUNK];
    int end = cbase[(k + 1) * NB_CHUNK];
    for (int e = beg + (int)threadIdx.x; e < end; e += 256) {
        int v = cw[e];
        int pos = atomicAdd(&cur[(v >> 24) & 255], 1); // LDS atomic; pos is global index
        col[pos] = v & 0x00FFFFFF;
    }
}

// ---------------- GEMM1: [M,256] @ [256,64] -> fp16 [M,64] ----------------
// Both operands LDS-staged; x-tile stored TRANSPOSED ([k][row]) so the a-operand
// is one ds_read_b128 per kk (round 7's 4 scalar reads were the LDS bottleneck).
// 4x8 register tile, 256 threads, BM=128 -> 782 blocks x 4 waves = 12 waves/CU.
__global__ __launch_bounds__(256) void gemm1_kernel(const float* __restrict__ x,
                                                    const float* __restrict__ W,
                                                    __half* __restrict__ H, int M) {
    __shared__ float xs_t[32][128];    // [k][row], 16KB
    __shared__ float ws[32][64];       // 8KB
    int tid = threadIdx.x;
    int tx = tid & 7;                  // 8 col-groups of 8
    int ty = tid >> 3;                 // 32 row-groups of 4
    int bm = blockIdx.x * 128;
    const float4* x4 = reinterpret_cast<const float4*>(x);
    float acc[4][8] = {};
    for (int kt = 0; kt < 8; ++kt) {   // K tiles of 32
        // stage x-tile transposed: 1024 float4 / 256 thr = 4 each
#pragma unroll
        for (int i = 0; i < 4; ++i) {
            int lin = i * 256 + tid;
            int row = lin & 127;
            int kg  = lin >> 7;        // 0..7 (float4 groups of k)
            int gr = bm + row;
            float4 v = make_float4(0.f, 0.f, 0.f, 0.f);
            if (gr < M) v = x4[(size_t)gr * 64 + kt * 8 + kg];
            xs_t[kg * 4 + 0][row] = v.x;
            xs_t[kg * 4 + 1][row] = v.y;
            xs_t[kg * 4 + 2][row] = v.z;
            xs_t[kg * 4 + 3][row] = v.w;
        }
        // stage W-tile: 512 float4 / 256 thr = 2 each
#pragma unroll
        for (int i = 0; i < 2; ++i) {
            int lin = i * 256 + tid;
            int r = lin >> 4;
            int c = (lin & 15) << 2;
            *reinterpret_cast<float4*>(&ws[r][c]) =
                *reinterpret_cast<const float4*>(&W[(size_t)(kt * 32 + r) * 64 + c]);
        }
        __syncthreads();
#pragma unroll 8
        for (int kk = 0; kk < 32; ++kk) {
            float4 a  = *reinterpret_cast<const float4*>(&xs_t[kk][ty * 4]);
            float4 b0 = *reinterpret_cast<const float4*>(&ws[kk][tx * 8]);
            float4 b1 = *reinterpret_cast<const float4*>(&ws[kk][tx * 8 + 4]);
            float av[4] = {a.x, a.y, a.z, a.w};
            float bv[8] = {b0.x, b0.y, b0.z, b0.w, b1.x, b1.y, b1.z, b1.w};
#pragma unroll
            for (int i = 0; i < 4; ++i)
#pragma unroll
                for (int j = 0; j < 8; ++j)
                    acc[i][j] = fmaf(av[i], bv[j], acc[i][j]);
        }
        __syncthreads();
    }
#pragma unroll
    for (int i = 0; i < 4; ++i) {
        int gr = bm + ty * 4 + i;
        if (gr >= M) continue;
        __half hv[8];
#pragma unroll
        for (int j = 0; j < 8; ++j) hv[j] = __float2half(acc[i][j]);
        *reinterpret_cast<uint4*>(&H[(size_t)gr * 64 + tx * 8]) =
            *reinterpret_cast<const uint4*>(hv);
    }
}

// ---------------- aggregation: fp16 gathers, 8-lane groups (8 edges/instr) ----------------
// out[i,:] = dinv[i]*(sum_j dinv[col_j]*h[col_j,:] + dinv[i]*h[i,:]) (+bias, relu)
// h is fp16 [n][64]; group g=lane>>3 takes edges p=start+g, start+g+8, ...
// each lane covers 8 features (16B uint4 = 8 halves). fp32 accumulate.
__global__ __launch_bounds__(256) void aggregate_kernel(const __half* __restrict__ h,
                                                        const int* __restrict__ ptr,
                                                        const int* __restrict__ col,
                                                        const float* __restrict__ dinv,
                                                        const float* __restrict__ bias,
                                                        void* __restrict__ out, int n,
                                                        int relu, int out_half) {
    int node = (blockIdx.x << 2) + (threadIdx.x >> 6);
    if (node >= n) return;
    int lane = threadIdx.x & 63;
    int g  = lane >> 3;               // edge-group 0..7
    int fl = (lane & 7) << 3;         // feature base: 0,8,...,56
    float acc[8] = {};
    int pend = ptr[node + 1];
    int p = ptr[node] + g;
    for (; p + 8 < pend; p += 16) {   // unroll 2: 16 edges in flight per wave
        int c0 = col[p];
        int c1 = col[p + 8];
        uint4 r0 = *reinterpret_cast<const uint4*>(&h[(size_t)c0 * 64 + fl]);
        uint4 r1 = *reinterpret_cast<const uint4*>(&h[(size_t)c1 * 64 + fl]);
        float w0 = dinv[c0], w1 = dinv[c1];
        const unsigned* u0 = &r0.x;
        const unsigned* u1 = &r1.x;
#pragma unroll
        for (int k = 0; k < 4; ++k) {
            float2 f0 = __half22float2(*reinterpret_cast<const __half2*>(&u0[k]));
            float2 f1 = __half22float2(*reinterpret_cast<const __half2*>(&u1[k]));
            acc[2 * k]     = fmaf(w0, f0.x, acc[2 * k]);
            acc[2 * k + 1] = fmaf(w0, f0.y, acc[2 * k + 1]);
            acc[2 * k]     = fmaf(w1, f1.x, acc[2 * k]);
            acc[2 * k + 1] = fmaf(w1, f1.y, acc[2 * k + 1]);
        }
    }
    if (p < pend) {
        int c0 = col[p];
        uint4 r0 = *reinterpret_cast<const uint4*>(&h[(size_t)c0 * 64 + fl]);
        float w0 = dinv[c0];
        const unsigned* u0 = &r0.x;
#pragma unroll
        for (int k = 0; k < 4; ++k) {
            float2 f0 = __half22float2(*reinterpret_cast<const __half2*>(&u0[k]));
            acc[2 * k]     = fmaf(w0, f0.x, acc[2 * k]);
            acc[2 * k + 1] = fmaf(w0, f0.y, acc[2 * k + 1]);
        }
    }
    // combine the 8 group partial sums (butterfly over lane bits 3,4,5)
#pragma unroll
    for (int j = 0; j < 8; ++j) {
        acc[j] += __shfl_xor(acc[j], 8, 64);
        acc[j] += __shfl_xor(acc[j], 16, 64);
        acc[j] += __shfl_xor(acc[j], 32, 64);
    }
    if (g == 0) {                     // lanes 0..7 own the epilogue
        float di = dinv[node];
        uint4 sv = *reinterpret_cast<const uint4*>(&h[(size_t)node * 64 + fl]);
        const unsigned* su = &sv.x;
        float v[8];
#pragma unroll
        for (int k = 0; k < 4; ++k) {
            float2 f = __half22float2(*reinterpret_cast<const __half2*>(&su[k]));
            v[2 * k]     = fmaf(di, f.x, acc[2 * k]) * di;
            v[2 * k + 1] = fmaf(di, f.y, acc[2 * k + 1]) * di;
        }
        if (bias) {
            float4 b0 = *reinterpret_cast<const float4*>(&bias[fl]);
            float4 b1 = *reinterpret_cast<const float4*>(&bias[fl + 4]);
            v[0] += b0.x; v[1] += b0.y; v[2] += b0.z; v[3] += b0.w;
            v[4] += b1.x; v[5] += b1.y; v[6] += b1.z; v[7] += b1.w;
        }
        if (relu) {
#pragma unroll
            for (int j = 0; j < 8; ++j) v[j] = fmaxf(v[j], 0.f);
        }
        if (out_half) {
            __half hv[8];
#pragma unroll
            for (int j = 0; j < 8; ++j) hv[j] = __float2half(v[j]);
            *reinterpret_cast<uint4*>(&((__half*)out)[(size_t)node * 64 + fl]) =
                *reinterpret_cast<const uint4*>(hv);
        } else {
            float* fo = (float*)out;
            *reinterpret_cast<float4*>(&fo[(size_t)node * 64 + fl]) =
                make_float4(v[0], v[1], v[2], v[3]);
            *reinterpret_cast<float4*>(&fo[(size_t)node * 64 + fl + 4]) =
                make_float4(v[4], v[5], v[6], v[7]);
        }
    }
}

// ---------------- GEMM2: [M,64] @ [64,128] + b -> [M,128] ----------------
__global__ __launch_bounds__(256) void gemm2_kernel(const float* __restrict__ A,
                                                    const float* __restrict__ W,
                                                    const float* __restrict__ bias,
                                                    float* __restrict__ out, int M) {
    __shared__ float as[64][65];
    __shared__ float ws[64][128];
    int tid = threadIdx.x;
    int bm = blockIdx.x * 64;
    int ty = tid >> 4, tx = tid & 15;
#pragma unroll
    for (int i = 0; i < 4; ++i) {
        int lin = (tid << 2) + i;
        int r = lin >> 4;
        int c = (lin & 15) << 2;
        float4 v = make_float4(0.f, 0.f, 0.f, 0.f);
        int gr = bm + r;
        if (gr < M) v = *reinterpret_cast<const float4*>(&A[(size_t)gr * 64 + c]);
        as[r][c] = v.x; as[r][c + 1] = v.y; as[r][c + 2] = v.z; as[r][c + 3] = v.w;
    }
#pragma unroll
    for (int i = 0; i < 8; ++i) {
        int lin = tid + (i << 8);
        int r = lin >> 5;
        int c = (lin & 31) << 2;
        *reinterpret_cast<float4*>(&ws[r][c]) =
            *reinterpret_cast<const float4*>(&W[(size_t)r * 128 + c]);
    }
    __syncthreads();
    float acc[4][8] = {};
#pragma unroll 8
    for (int kk = 0; kk < 64; ++kk) {
        float a[4];
#pragma unroll
        for (int i = 0; i < 4; ++i) a[i] = as[ty * 4 + i][kk];
        float b[8];
        float4 b0 = *reinterpret_cast<const float4*>(&ws[kk][tx * 8]);
        float4 b1 = *reinterpret_cast<const float4*>(&ws[kk][tx * 8 + 4]);
        b[0] = b0.x; b[1] = b0.y; b[2] = b0.z; b[3] = b0.w;
        b[4] = b1.x; b[5] = b1.y; b[6] = b1.z; b[7] = b1.w;
#pragma unroll
        for (int i = 0; i < 4; ++i)
#pragma unroll
            for (int j = 0; j < 8; ++j)
                acc[i][j] = fmaf(a[i], b[j], acc[i][j]);
    }
#pragma unroll
    for (int i = 0; i < 4; ++i) {
        int gr = bm + ty * 4 + i;
        if (gr >= M) continue;
#pragma unroll
        for (int jv = 0; jv < 2; ++jv) {
            int cbase = tx * 8 + jv * 4;
            float4 o;
            o.x = acc[i][jv * 4 + 0] + bias[cbase + 0];
            o.y = acc[i][jv * 4 + 1] + bias[cbase + 1];
            o.z = acc[i][jv * 4 + 2] + bias[cbase + 2];
            o.w = acc[i][jv * 4 + 3] + bias[cbase + 3];
            *reinterpret_cast<float4*>(&out[(size_t)gr * 128 + cbase]) = o;
        }
    }
}

extern "C" void kernel_launch(void* const* d_in, const int* in_sizes, int n_in,
                              void* d_out, int out_size, void* d_ws, size_t ws_size,
                              hipStream_t stream) {
    const float* x  = (const float*)d_in[0];
    const int*   ei = (const int*)d_in[1];
    const float* W1 = (const float*)d_in[2];
    const float* b1 = (const float*)d_in[3];
    const float* W2 = (const float*)d_in[4];
    const float* b2 = (const float*)d_in[5];
    float* out = (float*)d_out;
    const int n = NNODES;
    const int E = in_sizes[1] / 2;
    const int CE = (E + NB_CHUNK - 1) / NB_CHUNK;

    char* w = (char*)d_ws;
    auto alloc = [&](size_t bytes) {
        char* p = w;
        w += (bytes + 255) & ~(size_t)255;
        return p;
    };
    int*    flag   = (int*)   alloc(4);
    int*    counts = (int*)   alloc((size_t)NC * 4);
    int*    cbase  = (int*)   alloc((size_t)(NC + 1) * 4);
    int*    indeg  = (int*)   alloc((size_t)n * 4);
    float*  dinv   = (float*) alloc((size_t)n * 4);
    int*    ptr    = (int*)   alloc((size_t)(n + 1) * 4);
    int*    bsum   = (int*)   alloc(128 * 4);
    int*    boff   = (int*)   alloc(128 * 4);
    int*    cw     = (int*)   alloc((size_t)E * 4);
    int*    col    = (int*)   alloc((size_t)E * 4);
    __half* H1     = (__half*)alloc((size_t)n * 64 * 2);
    __half* h1     = (__half*)alloc((size_t)n * 64 * 2);
    float*  A2     = (float*) alloc((size_t)n * 64 * 4);

    int sbC = (NC + SCAN_ELEMS - 1) / SCAN_ELEMS;   // 98
    int sbN = (n  + SCAN_ELEMS - 1) / SCAN_ELEMS;   // 98

    detect_kernel<<<1, 128, 0, stream>>>(ei, flag);
    count_kernel<<<NB_CHUNK, 256, 0, stream>>>(ei, counts, E, CE, flag);
    scan_partial_kernel<<<sbC, 256, 0, stream>>>(counts, bsum, NC);
    scan_partials_kernel<<<1, 128, 0, stream>>>(bsum, boff, &cbase[NC], sbC);
    scan_write_kernel<<<sbC, 256, 0, stream>>>(counts, boff, cbase, NC);
    scatter_kernel<<<NB_CHUNK, 256, 0, stream>>>(ei, cbase, cw, E, CE, flag);
    histdeg_kernel<<<NBUCK, 256, 0, stream>>>(cw, cbase, indeg, dinv, n);
    scan_partial_kernel<<<sbN, 256, 0, stream>>>(indeg, bsum, n);
    scan_partials_kernel<<<1, 128, 0, stream>>>(bsum, boff, &ptr[n], sbN);
    scan_write_kernel<<<sbN, 256, 0, stream>>>(indeg, boff, ptr, n);
    fillcol_kernel<<<NBUCK, 256, 0, stream>>>(cw, cbase, ptr, col, n);

    gemm1_kernel<<<(n + 127) / 128, 256, 0, stream>>>(x, W1, H1, n);
    aggregate_kernel<<<(n + 3) / 4, 256, 0, stream>>>(H1, ptr, col, dinv, b1, h1, n, 1, 1);
    aggregate_kernel<<<(n + 3) / 4, 256, 0, stream>>>(h1, ptr, col, dinv, nullptr, A2, n, 0, 0);
    gemm2_kernel<<<(n + 63) / 64, 256, 0, stream>>>(A2, W2, b2, out, n);
}